// Round 3
// baseline (120.546 us; speedup 1.0000x reference)
//
#include <hip/hip_runtime.h>
#include <math.h>

#define BB 8
#define CC 64
#define NN 4096
#define CI 8
#define GAMMA 0.1f
// exp(s/sqrt(8)) = exp2(s * log2(e)/sqrt(8)); folded into k in qkv.
#define SCALE (1.44269504088896f * 0.35355339059327f)
#define NSPLIT 16

typedef float v4f  __attribute__((ext_vector_type(4)));
typedef float v16f __attribute__((ext_vector_type(16)));
typedef __bf16 bf16x8 __attribute__((ext_vector_type(8)));
typedef unsigned int u32x2 __attribute__((ext_vector_type(2)));

__device__ __forceinline__ float fast_exp2(float x) {
    return __builtin_amdgcn_exp2f(x);
}

// Pack two f32 into one u32 of 2 bf16 (T12 recipe; no builtin on gfx950).
__device__ __forceinline__ unsigned int cvt_pk_bf16(float lo, float hi) {
    unsigned int r;
    asm("v_cvt_pk_bf16_f32 %0, %1, %2" : "=v"(r) : "v"(lo), "v"(hi));
    return r;
}

// R7-proven qkv (round-0 exact). Grid (NN/32, BB); block 256 = 8 i-groups x 32 n.
// qbh[b][n][8], kbh[b][m][8] (k*SCALE), vbh[b][i][N] bf16; zeros attab[b][9][N].
__global__ __launch_bounds__(256) void qkv_kernel(
        const float* __restrict__ x,
        const float* __restrict__ Wq, const float* __restrict__ Wk,
        const float* __restrict__ Wv,
        __bf16* __restrict__ qbh, __bf16* __restrict__ kbh,
        __bf16* __restrict__ vbh, float* __restrict__ attab) {
    __shared__ float sw[3 * CI * CC];     // 6 KB: Wq | Wk*SCALE | Wv
    __shared__ unsigned short sq[32 * 8]; // bf16 tile [n_local][i]
    __shared__ unsigned short sk[32 * 8];
    const int t = threadIdx.x;
    const int i  = t >> 5;
    const int nl = t & 31;
    const int b  = blockIdx.y;
    const int n0 = blockIdx.x * 32;

    for (int idx = t; idx < CI * CC; idx += 256) {
        sw[idx]                = Wq[idx];
        sw[CI * CC + idx]      = Wk[idx] * SCALE;
        sw[2 * CI * CC + idx]  = Wv[idx];
    }
    int lin = (blockIdx.y * (NN / 32) + blockIdx.x) * 256 + t;
    for (int idx = lin; idx < BB * 9 * NN; idx += BB * NN * CI) attab[idx] = 0.f;
    __syncthreads();

    const int n = n0 + nl;
    const float* xp = x + ((size_t)b * CC) * NN + n;
    const v4f* wq4 = (const v4f*)(sw + i * CC);
    const v4f* wk4 = (const v4f*)(sw + CI * CC + i * CC);
    const v4f* wv4 = (const v4f*)(sw + 2 * CI * CC + i * CC);
    float qa = 0.f, ka = 0.f, va = 0.f;
#pragma unroll 4
    for (int c4 = 0; c4 < CC / 4; ++c4) {
        v4f wq = wq4[c4], wk = wk4[c4], wv = wv4[c4];   // LDS broadcast b128
        float x0 = xp[(size_t)(c4 * 4 + 0) * NN];
        float x1 = xp[(size_t)(c4 * 4 + 1) * NN];
        float x2 = xp[(size_t)(c4 * 4 + 2) * NN];
        float x3 = xp[(size_t)(c4 * 4 + 3) * NN];
        qa = fmaf(wq.x, x0, qa); ka = fmaf(wk.x, x0, ka); va = fmaf(wv.x, x0, va);
        qa = fmaf(wq.y, x1, qa); ka = fmaf(wk.y, x1, ka); va = fmaf(wv.y, x1, va);
        qa = fmaf(wq.z, x2, qa); ka = fmaf(wk.z, x2, ka); va = fmaf(wv.z, x2, va);
        qa = fmaf(wq.w, x3, qa); ka = fmaf(wk.w, x3, ka); va = fmaf(wv.w, x3, va);
    }
    __bf16 vb = (__bf16)va;
    vbh[((size_t)b * CI + i) * NN + n] = vb;
    __bf16 qb = (__bf16)qa, kb2 = (__bf16)ka;
    sq[nl * 8 + i] = *(unsigned short*)&qb;
    sk[nl * 8 + i] = *(unsigned short*)&kb2;
    __syncthreads();
    if (t < 32) {
        *(uint4*)(qbh + ((size_t)b * NN + n0 + t) * 8) = *(const uint4*)(sq + t * 8);
        *(uint4*)(kbh + ((size_t)b * NN + n0 + t) * 8) = *(const uint4*)(sk + t * 8);
    }
}

// 32x32-tile MFMA attention, LDS-free (cvt_pk + permlane32_swap transpose).
// Round-2 post-mortem: round-1's ternary V loads were ALREADY if-converted
// (loads wave-wide, cndmask selects) and cheap (ln&7 aliasing -> only 8
// distinct broadcast addresses); the 64-lane vt gather regressed. This round:
//  (a) GARBAGE-ROWS TRICK: PV C-rows 9..31 are never read, and row 8 (the
//      softmax denominator) is computed directly from the in-register exp
//      values (den += sum(e), one shfl_xor(32) in the epilogue). So the PV
//      A-frag rows 8..31 may hold ANYTHING -> va loads are unconditional
//      vrow(ln&7) broadcasts, zero cndmask, no ones/zero constant regs.
//  (b) qf unconditional (hi=1 half multiplies zeroed K rows).
//  (c) NSPLIT 16 -> 4096 blocks: 2x backlog so the scheduler refills CUs
//      (round-0 occupancy was 50% with no resource limit -> no-tail-refill).
//  (d) T5 s_setprio(1) around S and PV MFMAs (m191: +4-7% on independent-wave
//      attention).
//  (e) single accumulator, no prefetch/unroll -> VGPR <= 64, 8 waves/SIMD.
// S C-layout (HW-verified): col=lane&31, row=(reg&3)+8*(reg>>2)+4*(lane>>5).
// |scores| < ~2 -> exp without max-subtraction safe.
// Grid (NN/128, NSPLIT, BB) = 4096 blocks x 4 waves; wave = 32-m x 256-n tile.
__global__ __launch_bounds__(256) void att_kernel(
        const __bf16* __restrict__ qbh, const __bf16* __restrict__ kbh,
        const __bf16* __restrict__ vbh, float* __restrict__ attab) {
    const int t = threadIdx.x;
    const int w    = t >> 6;
    const int l    = t & 63;
    const int ln   = l & 31;        // S: A-row (n) / B-col (m); C col (m)
    const int hi   = l >> 5;        // k-half selector (k = hi*8 + j)
    const int b  = blockIdx.z;
    const int m0 = blockIdx.x * 128 + w * 32;
    const int nbase = blockIdx.y * (NN / NSPLIT);   // 256 per wave
    const int NCH = (NN / NSPLIT) / 32;             // 8 chunks of 32 n

    bf16x8 zero8;
#pragma unroll
    for (int z = 0; z < 8; ++z) zero8[z] = (__bf16)0.0f;
    const v16f vzero = {0.f,0.f,0.f,0.f,0.f,0.f,0.f,0.f,
                        0.f,0.f,0.f,0.f,0.f,0.f,0.f,0.f};

    // S B-frag (loop-invariant): B[k=hi*8+j][col=ln] = K[m0+ln][j], hi==0 live.
    // k=8..15 rows ZERO -> the hi=1 half of the A-frag may hold anything.
    bf16x8 kfragB = hi ? zero8
                       : *(const bf16x8*)(kbh + ((size_t)b * NN + m0 + ln) * 8);

    const __bf16* qrow = qbh + (size_t)b * NN * 8;
    // PV A-frag row = ln; rows 8..31 alias rows 0..7 (garbage rows, C 8..31
    // never read). 8 distinct addresses -> HW broadcast load.
    const __bf16* vrow = vbh + ((size_t)b * CI + (ln & 7)) * NN;

    v16f acc = vzero;
    float den = 0.f;

    for (int ch = 0; ch < NCH; ++ch) {
        const int nc = nbase + ch * 32;
        bf16x8 qf  = *(const bf16x8*)(qrow + (size_t)(nc + ln) * 8);
        bf16x8 va0 = *(const bf16x8*)(vrow + nc + hi * 8);
        bf16x8 va1 = *(const bf16x8*)(vrow + nc + 16 + hi * 8);

        __builtin_amdgcn_s_setprio(1);
        v16f S = __builtin_amdgcn_mfma_f32_32x32x16_bf16(qf, kfragB, vzero,
                                                         0, 0, 0);
        __builtin_amdgcn_s_setprio(0);

        float e0  = fast_exp2(S[0]),  e1  = fast_exp2(S[1]);
        float e2  = fast_exp2(S[2]),  e3  = fast_exp2(S[3]);
        float e4  = fast_exp2(S[4]),  e5  = fast_exp2(S[5]);
        float e6  = fast_exp2(S[6]),  e7  = fast_exp2(S[7]);
        float e8  = fast_exp2(S[8]),  e9  = fast_exp2(S[9]);
        float e10 = fast_exp2(S[10]), e11 = fast_exp2(S[11]);
        float e12 = fast_exp2(S[12]), e13 = fast_exp2(S[13]);
        float e14 = fast_exp2(S[14]), e15 = fast_exp2(S[15]);

        // Denominator partial for col m=ln (16 n-values this lane holds).
        den += (((e0 + e1) + (e2 + e3)) + ((e4 + e5) + (e6 + e7)))
             + (((e8 + e9) + (e10 + e11)) + ((e12 + e13) + (e14 + e15)));

        unsigned int pk0 = cvt_pk_bf16(e0,  e1);
        unsigned int pk1 = cvt_pk_bf16(e2,  e3);
        unsigned int pk2 = cvt_pk_bf16(e4,  e5);
        unsigned int pk3 = cvt_pk_bf16(e6,  e7);
        unsigned int pk4 = cvt_pk_bf16(e8,  e9);
        unsigned int pk5 = cvt_pk_bf16(e10, e11);
        unsigned int pk6 = cvt_pk_bf16(e12, e13);
        unsigned int pk7 = cvt_pk_bf16(e14, e15);

        // Lane-half exchange -> PV B-frags B[k=hi*8+j][col=ln] = E[n][m]
        u32x2 r02 = __builtin_amdgcn_permlane32_swap(pk0, pk2, false, false);
        u32x2 r13 = __builtin_amdgcn_permlane32_swap(pk1, pk3, false, false);
        u32x2 r46 = __builtin_amdgcn_permlane32_swap(pk4, pk6, false, false);
        u32x2 r57 = __builtin_amdgcn_permlane32_swap(pk5, pk7, false, false);

        union { unsigned int u[4]; bf16x8 f; } e0f, e1f;
        e0f.u[0] = r02[0]; e0f.u[1] = r13[0]; e0f.u[2] = r02[1]; e0f.u[3] = r13[1];
        e1f.u[0] = r46[0]; e1f.u[1] = r57[0]; e1f.u[2] = r46[1]; e1f.u[3] = r57[1];

        __builtin_amdgcn_s_setprio(1);
        acc = __builtin_amdgcn_mfma_f32_32x32x16_bf16(va0, e0f.f, acc, 0, 0, 0);
        acc = __builtin_amdgcn_mfma_f32_32x32x16_bf16(va1, e1f.f, acc, 0, 0, 0);
        __builtin_amdgcn_s_setprio(0);
    }

    // Epilogue: C row io=(r&3)+8*(r>>2)+4*hi -> r=0..3 give rows 0..7 (= V
    // outputs); rows 8..31 are garbage (skipped). Denominator row 8 from den.
    float* ap = attab + (size_t)b * 9 * NN + m0 + ln;
#pragma unroll
    for (int r = 0; r < 4; ++r)
        atomicAdd(ap + (size_t)(r + 4 * hi) * NN, acc[r]);
    float dtot = den + __shfl_xor(den, 32, 64);
    if (hi == 0)
        atomicAdd(ap + (size_t)8 * NN, dtot);
}

// R7-proven out. Grid (NN/1024, CC, BB); block 256; float4 per thread.
__global__ __launch_bounds__(256) void out_kernel(
        const float* __restrict__ x, const float* __restrict__ Wout,
        const float* __restrict__ attab, float* __restrict__ out) {
    const int t = threadIdx.x;
    const int c = blockIdx.y;
    const int b = blockIdx.z;
    const int m = (blockIdx.x * 256 + t) * 4;
    const float* ap = attab + (size_t)b * 9 * NN + m;
    v4f sum = *(const v4f*)(ap + (size_t)8 * NN);
    v4f s = {0.f, 0.f, 0.f, 0.f};
#pragma unroll
    for (int i = 0; i < CI; ++i) {
        float wgt = Wout[c * CI + i];               // uniform -> s_load
        v4f a = *(const v4f*)(ap + (size_t)i * NN);
        s.x = fmaf(wgt, a.x, s.x);
        s.y = fmaf(wgt, a.y, s.y);
        s.z = fmaf(wgt, a.z, s.z);
        s.w = fmaf(wgt, a.w, s.w);
    }
    size_t o = ((size_t)b * CC + c) * NN + m;
    v4f xv = *(const v4f*)(x + o);
    v4f r;
    r.x = xv.x + GAMMA * (s.x / sum.x);
    r.y = xv.y + GAMMA * (s.y / sum.y);
    r.z = xv.z + GAMMA * (s.z / sum.z);
    r.w = xv.w + GAMMA * (s.w / sum.w);
    *(v4f*)(out + o) = r;
}

extern "C" void kernel_launch(void* const* d_in, const int* in_sizes, int n_in,
                              void* d_out, int out_size, void* d_ws, size_t ws_size,
                              hipStream_t stream) {
    const float* x    = (const float*)d_in[0];
    const float* Wq   = (const float*)d_in[1];
    const float* Wk   = (const float*)d_in[2];
    const float* Wv   = (const float*)d_in[3];
    const float* Wout = (const float*)d_in[4];
    float* out = (float*)d_out;

    // ws: qbh [B][N][8] bf16 | kbh [B][N][8] bf16 | vbh [B][8][N] bf16 |
    //     attab [B][9][N] fp32
    __bf16* qbh = (__bf16*)d_ws;
    __bf16* kbh = qbh + (size_t)BB * NN * 8;
    __bf16* vbh = kbh + (size_t)BB * NN * 8;
    float* attab = (float*)(vbh + (size_t)BB * NN * 8);

    qkv_kernel<<<dim3(NN / 32, BB), 256, 0, stream>>>(x, Wq, Wk, Wv, qbh, kbh, vbh, attab);
    att_kernel<<<dim3(NN / 128, NSPLIT, BB), 256, 0, stream>>>(qbh, kbh, vbh, attab);
    out_kernel<<<dim3(NN / 1024, CC, BB), 256, 0, stream>>>(x, Wout, attab, out);
}

// Round 4
// 115.788 us; speedup vs baseline: 1.0411x; 1.0411x over previous
//
#include <hip/hip_runtime.h>
#include <math.h>

#define BB 8
#define CC 64
#define NN 4096
#define CI 8
#define GAMMA 0.1f
// exp(s/sqrt(8)) = exp2(s * log2(e)/sqrt(8)); folded into k in qkv.
#define SCALE (1.44269504088896f * 0.35355339059327f)
#define NSPLIT 8

typedef float v4f  __attribute__((ext_vector_type(4)));
typedef float v16f __attribute__((ext_vector_type(16)));
typedef __bf16 bf16x8 __attribute__((ext_vector_type(8)));
typedef unsigned int u32x2 __attribute__((ext_vector_type(2)));

__device__ __forceinline__ float fast_exp2(float x) {
    return __builtin_amdgcn_exp2f(x);
}

// Pack two f32 into one u32 of 2 bf16 (T12 recipe; no builtin on gfx950).
__device__ __forceinline__ unsigned int cvt_pk_bf16(float lo, float hi) {
    unsigned int r;
    asm("v_cvt_pk_bf16_f32 %0, %1, %2" : "=v"(r) : "v"(lo), "v"(hi));
    return r;
}

// R7-proven qkv (round-0 exact). Grid (NN/32, BB); block 256 = 8 i-groups x 32 n.
// qbh[b][n][8], kbh[b][m][8] (k*SCALE), vbh[b][i][N] bf16; zeros attab[b][9][N].
__global__ __launch_bounds__(256) void qkv_kernel(
        const float* __restrict__ x,
        const float* __restrict__ Wq, const float* __restrict__ Wk,
        const float* __restrict__ Wv,
        __bf16* __restrict__ qbh, __bf16* __restrict__ kbh,
        __bf16* __restrict__ vbh, float* __restrict__ attab) {
    __shared__ float sw[3 * CI * CC];     // 6 KB: Wq | Wk*SCALE | Wv
    __shared__ unsigned short sq[32 * 8]; // bf16 tile [n_local][i]
    __shared__ unsigned short sk[32 * 8];
    const int t = threadIdx.x;
    const int i  = t >> 5;
    const int nl = t & 31;
    const int b  = blockIdx.y;
    const int n0 = blockIdx.x * 32;

    for (int idx = t; idx < CI * CC; idx += 256) {
        sw[idx]                = Wq[idx];
        sw[CI * CC + idx]      = Wk[idx] * SCALE;
        sw[2 * CI * CC + idx]  = Wv[idx];
    }
    int lin = (blockIdx.y * (NN / 32) + blockIdx.x) * 256 + t;
    for (int idx = lin; idx < BB * 9 * NN; idx += BB * NN * CI) attab[idx] = 0.f;
    __syncthreads();

    const int n = n0 + nl;
    const float* xp = x + ((size_t)b * CC) * NN + n;
    const v4f* wq4 = (const v4f*)(sw + i * CC);
    const v4f* wk4 = (const v4f*)(sw + CI * CC + i * CC);
    const v4f* wv4 = (const v4f*)(sw + 2 * CI * CC + i * CC);
    float qa = 0.f, ka = 0.f, va = 0.f;
#pragma unroll 4
    for (int c4 = 0; c4 < CC / 4; ++c4) {
        v4f wq = wq4[c4], wk = wk4[c4], wv = wv4[c4];   // LDS broadcast b128
        float x0 = xp[(size_t)(c4 * 4 + 0) * NN];
        float x1 = xp[(size_t)(c4 * 4 + 1) * NN];
        float x2 = xp[(size_t)(c4 * 4 + 2) * NN];
        float x3 = xp[(size_t)(c4 * 4 + 3) * NN];
        qa = fmaf(wq.x, x0, qa); ka = fmaf(wk.x, x0, ka); va = fmaf(wv.x, x0, va);
        qa = fmaf(wq.y, x1, qa); ka = fmaf(wk.y, x1, ka); va = fmaf(wv.y, x1, va);
        qa = fmaf(wq.z, x2, qa); ka = fmaf(wk.z, x2, ka); va = fmaf(wv.z, x2, va);
        qa = fmaf(wq.w, x3, qa); ka = fmaf(wk.w, x3, ka); va = fmaf(wv.w, x3, va);
    }
    __bf16 vb = (__bf16)va;
    vbh[((size_t)b * CI + i) * NN + n] = vb;
    __bf16 qb = (__bf16)qa, kb2 = (__bf16)ka;
    sq[nl * 8 + i] = *(unsigned short*)&qb;
    sk[nl * 8 + i] = *(unsigned short*)&kb2;
    __syncthreads();
    if (t < 32) {
        *(uint4*)(qbh + ((size_t)b * NN + n0 + t) * 8) = *(const uint4*)(sq + t * 8);
        *(uint4*)(kbh + ((size_t)b * NN + n0 + t) * 8) = *(const uint4*)(sk + t * 8);
    }
}

// 32x32-tile MFMA attention, LDS-free (cvt_pk + permlane32_swap transpose).
// Round-3 post-mortem: NSPLIT=16 doubled per-wave fixed overhead + atomic
// traffic, and single-acc/no-unroll left one serial S->exp->pack->swap->PV
// chain per wave (VALUBusy 48%, occupancy pinned ~49% in EVERY round).
// Round 4:
//  (a) NSPLIT back to 8 (NCH=16): half the waves, half the atomics/overhead.
//  (b) 512-thread blocks (8 waves): tests the blocks/CU occupancy cap; all
//      8 waves share one Q-range (better L1 reuse).
//  (c) dual accumulators + #pragma unroll 2: two independent chains in
//      flight; unconditional loads let the compiler hoist ch+1's loads
//      over ch's exp burst (no explicit prefetch regs -> VGPR stays low).
//  (d) no setprio (was bundled into the round-3 regression).
// Kept from round 3 (passed, absmax 0.0156): GARBAGE-ROWS trick (PV C rows
// 9..31 never read; den computed in-register, one shfl_xor(32) at the end;
// V loads = 8 distinct broadcast addresses, no cndmask), unconditional qf
// (hi=1 A-half multiplies zeroed K rows).
// S C-layout (HW-verified): col=lane&31, row=(reg&3)+8*(reg>>2)+4*(lane>>5).
// |scores| < ~2 -> exp without max-subtraction safe.
// Grid (NN/256, NSPLIT, BB) = 1024 blocks x 8 waves; wave = 32-m x 512-n tile.
__global__ __launch_bounds__(512) void att_kernel(
        const __bf16* __restrict__ qbh, const __bf16* __restrict__ kbh,
        const __bf16* __restrict__ vbh, float* __restrict__ attab) {
    const int t = threadIdx.x;
    const int w    = t >> 6;        // 0..7
    const int l    = t & 63;
    const int ln   = l & 31;        // S: A-row (n) / B-col (m); C col (m)
    const int hi   = l >> 5;        // k-half selector (k = hi*8 + j)
    const int b  = blockIdx.z;
    const int m0 = blockIdx.x * 256 + w * 32;
    const int nbase = blockIdx.y * (NN / NSPLIT);   // 512 per wave
    const int NCH = (NN / NSPLIT) / 32;             // 16 chunks of 32 n

    bf16x8 zero8;
#pragma unroll
    for (int z = 0; z < 8; ++z) zero8[z] = (__bf16)0.0f;
    const v16f vzero = {0.f,0.f,0.f,0.f,0.f,0.f,0.f,0.f,
                        0.f,0.f,0.f,0.f,0.f,0.f,0.f,0.f};

    // S B-frag (loop-invariant): B[k=hi*8+j][col=ln] = K[m0+ln][j], hi==0 live.
    // k=8..15 rows ZERO -> the hi=1 half of the A-frag may hold anything.
    bf16x8 kfragB = hi ? zero8
                       : *(const bf16x8*)(kbh + ((size_t)b * NN + m0 + ln) * 8);

    const __bf16* qrow = qbh + (size_t)b * NN * 8;
    // PV A-frag row = ln; rows 8..31 alias rows 0..7 (garbage rows, C 8..31
    // never read). 8 distinct addresses -> HW broadcast load.
    const __bf16* vrow = vbh + ((size_t)b * CI + (ln & 7)) * NN;

    v16f acc0 = vzero, acc1 = vzero;
    float den = 0.f;

#pragma unroll 2
    for (int ch = 0; ch < NCH; ++ch) {
        const int nc = nbase + ch * 32;
        bf16x8 qf  = *(const bf16x8*)(qrow + (size_t)(nc + ln) * 8);
        bf16x8 va0 = *(const bf16x8*)(vrow + nc + hi * 8);
        bf16x8 va1 = *(const bf16x8*)(vrow + nc + 16 + hi * 8);

        v16f S = __builtin_amdgcn_mfma_f32_32x32x16_bf16(qf, kfragB, vzero,
                                                         0, 0, 0);

        float e0  = fast_exp2(S[0]),  e1  = fast_exp2(S[1]);
        float e2  = fast_exp2(S[2]),  e3  = fast_exp2(S[3]);
        float e4  = fast_exp2(S[4]),  e5  = fast_exp2(S[5]);
        float e6  = fast_exp2(S[6]),  e7  = fast_exp2(S[7]);
        float e8  = fast_exp2(S[8]),  e9  = fast_exp2(S[9]);
        float e10 = fast_exp2(S[10]), e11 = fast_exp2(S[11]);
        float e12 = fast_exp2(S[12]), e13 = fast_exp2(S[13]);
        float e14 = fast_exp2(S[14]), e15 = fast_exp2(S[15]);

        // Denominator partial for col m=ln (16 n-values this lane holds).
        den += (((e0 + e1) + (e2 + e3)) + ((e4 + e5) + (e6 + e7)))
             + (((e8 + e9) + (e10 + e11)) + ((e12 + e13) + (e14 + e15)));

        unsigned int pk0 = cvt_pk_bf16(e0,  e1);
        unsigned int pk1 = cvt_pk_bf16(e2,  e3);
        unsigned int pk2 = cvt_pk_bf16(e4,  e5);
        unsigned int pk3 = cvt_pk_bf16(e6,  e7);
        unsigned int pk4 = cvt_pk_bf16(e8,  e9);
        unsigned int pk5 = cvt_pk_bf16(e10, e11);
        unsigned int pk6 = cvt_pk_bf16(e12, e13);
        unsigned int pk7 = cvt_pk_bf16(e14, e15);

        // Lane-half exchange -> PV B-frags B[k=hi*8+j][col=ln] = E[n][m]
        u32x2 r02 = __builtin_amdgcn_permlane32_swap(pk0, pk2, false, false);
        u32x2 r13 = __builtin_amdgcn_permlane32_swap(pk1, pk3, false, false);
        u32x2 r46 = __builtin_amdgcn_permlane32_swap(pk4, pk6, false, false);
        u32x2 r57 = __builtin_amdgcn_permlane32_swap(pk5, pk7, false, false);

        union { unsigned int u[4]; bf16x8 f; } e0f, e1f;
        e0f.u[0] = r02[0]; e0f.u[1] = r13[0]; e0f.u[2] = r02[1]; e0f.u[3] = r13[1];
        e1f.u[0] = r46[0]; e1f.u[1] = r57[0]; e1f.u[2] = r46[1]; e1f.u[3] = r57[1];

        if (ch & 1) {
            acc1 = __builtin_amdgcn_mfma_f32_32x32x16_bf16(va0, e0f.f, acc1, 0, 0, 0);
            acc1 = __builtin_amdgcn_mfma_f32_32x32x16_bf16(va1, e1f.f, acc1, 0, 0, 0);
        } else {
            acc0 = __builtin_amdgcn_mfma_f32_32x32x16_bf16(va0, e0f.f, acc0, 0, 0, 0);
            acc0 = __builtin_amdgcn_mfma_f32_32x32x16_bf16(va1, e1f.f, acc0, 0, 0, 0);
        }
    }

    // Epilogue: C row io = r + 4*hi for r=0..3 -> rows 0..7 (= V outputs);
    // rows 8..31 garbage (skipped). Denominator row 8 from den.
    float* ap = attab + (size_t)b * 9 * NN + m0 + ln;
#pragma unroll
    for (int r = 0; r < 4; ++r)
        atomicAdd(ap + (size_t)(r + 4 * hi) * NN, acc0[r] + acc1[r]);
    float dtot = den + __shfl_xor(den, 32, 64);
    if (hi == 0)
        atomicAdd(ap + (size_t)8 * NN, dtot);
}

// R7-proven out. Grid (NN/1024, CC, BB); block 256; float4 per thread.
__global__ __launch_bounds__(256) void out_kernel(
        const float* __restrict__ x, const float* __restrict__ Wout,
        const float* __restrict__ attab, float* __restrict__ out) {
    const int t = threadIdx.x;
    const int c = blockIdx.y;
    const int b = blockIdx.z;
    const int m = (blockIdx.x * 256 + t) * 4;
    const float* ap = attab + (size_t)b * 9 * NN + m;
    v4f sum = *(const v4f*)(ap + (size_t)8 * NN);
    v4f s = {0.f, 0.f, 0.f, 0.f};
#pragma unroll
    for (int i = 0; i < CI; ++i) {
        float wgt = Wout[c * CI + i];               // uniform -> s_load
        v4f a = *(const v4f*)(ap + (size_t)i * NN);
        s.x = fmaf(wgt, a.x, s.x);
        s.y = fmaf(wgt, a.y, s.y);
        s.z = fmaf(wgt, a.z, s.z);
        s.w = fmaf(wgt, a.w, s.w);
    }
    size_t o = ((size_t)b * CC + c) * NN + m;
    v4f xv = *(const v4f*)(x + o);
    v4f r;
    r.x = xv.x + GAMMA * (s.x / sum.x);
    r.y = xv.y + GAMMA * (s.y / sum.y);
    r.z = xv.z + GAMMA * (s.z / sum.z);
    r.w = xv.w + GAMMA * (s.w / sum.w);
    *(v4f*)(out + o) = r;
}

extern "C" void kernel_launch(void* const* d_in, const int* in_sizes, int n_in,
                              void* d_out, int out_size, void* d_ws, size_t ws_size,
                              hipStream_t stream) {
    const float* x    = (const float*)d_in[0];
    const float* Wq   = (const float*)d_in[1];
    const float* Wk   = (const float*)d_in[2];
    const float* Wv   = (const float*)d_in[3];
    const float* Wout = (const float*)d_in[4];
    float* out = (float*)d_out;

    // ws: qbh [B][N][8] bf16 | kbh [B][N][8] bf16 | vbh [B][8][N] bf16 |
    //     attab [B][9][N] fp32
    __bf16* qbh = (__bf16*)d_ws;
    __bf16* kbh = qbh + (size_t)BB * NN * 8;
    __bf16* vbh = kbh + (size_t)BB * NN * 8;
    float* attab = (float*)(vbh + (size_t)BB * NN * 8);

    qkv_kernel<<<dim3(NN / 32, BB), 256, 0, stream>>>(x, Wq, Wk, Wv, qbh, kbh, vbh, attab);
    att_kernel<<<dim3(NN / 256, NSPLIT, BB), 512, 0, stream>>>(qbh, kbh, vbh, attab);
    out_kernel<<<dim3(NN / 1024, CC, BB), 256, 0, stream>>>(x, Wout, attab, out);
}

// Round 5
// 113.208 us; speedup vs baseline: 1.0648x; 1.0228x over previous
//
#include <hip/hip_runtime.h>
#include <math.h>

#define BB 8
#define CC 64
#define NN 4096
#define CI 8
#define GAMMA 0.1f
// exp(s/sqrt(8)) = exp2(s * log2(e)/sqrt(8)); folded into k in qkv.
#define SCALE (1.44269504088896f * 0.35355339059327f)
#define NSPLIT 8

typedef float v4f  __attribute__((ext_vector_type(4)));
typedef float v16f __attribute__((ext_vector_type(16)));
typedef __bf16 bf16x8 __attribute__((ext_vector_type(8)));
typedef unsigned int u32x2 __attribute__((ext_vector_type(2)));

__device__ __forceinline__ float fast_exp2(float x) {
    return __builtin_amdgcn_exp2f(x);
}

// Pack two f32 into one u32 of 2 bf16 (T12 recipe; no builtin on gfx950).
__device__ __forceinline__ unsigned int cvt_pk_bf16(float lo, float hi) {
    unsigned int r;
    asm("v_cvt_pk_bf16_f32 %0, %1, %2" : "=v"(r) : "v"(lo), "v"(hi));
    return r;
}

// R7-proven qkv (round-0 exact). Grid (NN/32, BB); block 256 = 8 i-groups x 32 n.
// qbh[b][n][8], kbh[b][m][8] (k*SCALE), vbh[b][i][N] bf16; zeros attab[b][9][N].
__global__ __launch_bounds__(256) void qkv_kernel(
        const float* __restrict__ x,
        const float* __restrict__ Wq, const float* __restrict__ Wk,
        const float* __restrict__ Wv,
        __bf16* __restrict__ qbh, __bf16* __restrict__ kbh,
        __bf16* __restrict__ vbh, float* __restrict__ attab) {
    __shared__ float sw[3 * CI * CC];     // 6 KB: Wq | Wk*SCALE | Wv
    __shared__ unsigned short sq[32 * 8]; // bf16 tile [n_local][i]
    __shared__ unsigned short sk[32 * 8];
    const int t = threadIdx.x;
    const int i  = t >> 5;
    const int nl = t & 31;
    const int b  = blockIdx.y;
    const int n0 = blockIdx.x * 32;

    for (int idx = t; idx < CI * CC; idx += 256) {
        sw[idx]                = Wq[idx];
        sw[CI * CC + idx]      = Wk[idx] * SCALE;
        sw[2 * CI * CC + idx]  = Wv[idx];
    }
    int lin = (blockIdx.y * (NN / 32) + blockIdx.x) * 256 + t;
    for (int idx = lin; idx < BB * 9 * NN; idx += BB * NN * CI) attab[idx] = 0.f;
    __syncthreads();

    const int n = n0 + nl;
    const float* xp = x + ((size_t)b * CC) * NN + n;
    const v4f* wq4 = (const v4f*)(sw + i * CC);
    const v4f* wk4 = (const v4f*)(sw + CI * CC + i * CC);
    const v4f* wv4 = (const v4f*)(sw + 2 * CI * CC + i * CC);
    float qa = 0.f, ka = 0.f, va = 0.f;
#pragma unroll 4
    for (int c4 = 0; c4 < CC / 4; ++c4) {
        v4f wq = wq4[c4], wk = wk4[c4], wv = wv4[c4];   // LDS broadcast b128
        float x0 = xp[(size_t)(c4 * 4 + 0) * NN];
        float x1 = xp[(size_t)(c4 * 4 + 1) * NN];
        float x2 = xp[(size_t)(c4 * 4 + 2) * NN];
        float x3 = xp[(size_t)(c4 * 4 + 3) * NN];
        qa = fmaf(wq.x, x0, qa); ka = fmaf(wk.x, x0, ka); va = fmaf(wv.x, x0, va);
        qa = fmaf(wq.y, x1, qa); ka = fmaf(wk.y, x1, ka); va = fmaf(wv.y, x1, va);
        qa = fmaf(wq.z, x2, qa); ka = fmaf(wk.z, x2, ka); va = fmaf(wv.z, x2, va);
        qa = fmaf(wq.w, x3, qa); ka = fmaf(wk.w, x3, ka); va = fmaf(wv.w, x3, va);
    }
    __bf16 vb = (__bf16)va;
    vbh[((size_t)b * CI + i) * NN + n] = vb;
    __bf16 qb = (__bf16)qa, kb2 = (__bf16)ka;
    sq[nl * 8 + i] = *(unsigned short*)&qb;
    sk[nl * 8 + i] = *(unsigned short*)&kb2;
    __syncthreads();
    if (t < 32) {
        *(uint4*)(qbh + ((size_t)b * NN + n0 + t) * 8) = *(const uint4*)(sq + t * 8);
        *(uint4*)(kbh + ((size_t)b * NN + n0 + t) * 8) = *(const uint4*)(sk + t * 8);
    }
}

// 32x32-tile MFMA attention, LDS-free (cvt_pk + permlane32_swap transpose).
// Round-4 post-mortem: VALU-busy time is invariant ~12-13us across ALL
// configs; everything above it is issue-idle latency. The ONLY variant that
// beat 41us was round-1 (~36us), whose distinguishing feature was EXPLICIT
// wrap-indexed prefetch registers (manual hoisting of next-chunk loads above
// the exp burst; compiler unroll-2 alone does NOT do this -> round-4 lost it).
// Round 5 = merge of the two proven wins, nothing else:
//  - round-1 skeleton: 256-thread blocks, NSPLIT=8, explicit prefetch regs,
//    dual accumulators, #pragma unroll 2.
//  - round-3 garbage-rows: PV C-rows 9..31 never read -> V loads are
//    unconditional vrow(ln&7) broadcasts (no cndmask chain, no ones/zero
//    regs); denominator computed in-register (den += sum(e), one
//    shfl_xor(32)); epilogue = 4 atomics + 1 masked (was 9 in round-1).
//  - qf unconditional (hi=1 A-half multiplies zeroed K rows).
// No setprio (uncontrolled variable). OccupancyPercent is untrustworthy on
// gfx950 (gfx94x formula fallback) - not steering by it anymore.
// S C-layout (HW-verified): col=lane&31, row=(reg&3)+8*(reg>>2)+4*(lane>>5).
// |scores| < ~2 -> exp without max-subtraction safe.
// Grid (NN/128, NSPLIT, BB) = 2048 blocks x 4 waves; wave = 32-m x 512-n tile.
__global__ __launch_bounds__(256) void att_kernel(
        const __bf16* __restrict__ qbh, const __bf16* __restrict__ kbh,
        const __bf16* __restrict__ vbh, float* __restrict__ attab) {
    const int t = threadIdx.x;
    const int w    = t >> 6;
    const int l    = t & 63;
    const int ln   = l & 31;        // S: A-row (n) / B-col (m); C col (m)
    const int hi   = l >> 5;        // k-half selector (k = hi*8 + j)
    const int b  = blockIdx.z;
    const int m0 = blockIdx.x * 128 + w * 32;
    const int nbase = blockIdx.y * (NN / NSPLIT);   // 512 per wave
    const int NCH = (NN / NSPLIT) / 32;             // 16 chunks of 32 n

    bf16x8 zero8;
#pragma unroll
    for (int z = 0; z < 8; ++z) zero8[z] = (__bf16)0.0f;
    const v16f vzero = {0.f,0.f,0.f,0.f,0.f,0.f,0.f,0.f,
                        0.f,0.f,0.f,0.f,0.f,0.f,0.f,0.f};

    // S B-frag (loop-invariant): B[k=hi*8+j][col=ln] = K[m0+ln][j], hi==0 live.
    // k=8..15 rows ZERO -> the hi=1 half of the A-frag may hold anything.
    bf16x8 kfragB = hi ? zero8
                       : *(const bf16x8*)(kbh + ((size_t)b * NN + m0 + ln) * 8);

    const __bf16* qrow = qbh + (size_t)b * NN * 8;
    // PV A-frag row = ln; rows 8..31 alias rows 0..7 (garbage rows, C 8..31
    // never read). 8 distinct addresses -> HW broadcast load.
    const __bf16* vrow = vbh + ((size_t)b * CI + (ln & 7)) * NN;

    v16f acc0 = vzero, acc1 = vzero;
    float den = 0.f;

    // Prologue: chunk 0 loads (all unconditional).
    bf16x8 qf  = *(const bf16x8*)(qrow + (size_t)(nbase + ln) * 8);
    bf16x8 va0 = *(const bf16x8*)(vrow + nbase + hi * 8);
    bf16x8 va1 = *(const bf16x8*)(vrow + nbase + 16 + hi * 8);

#pragma unroll 2
    for (int ch = 0; ch < NCH; ++ch) {
        // Explicit prefetch of next chunk (wrap on last iter: uniform, cheap,
        // result discarded). This is the round-1 win: issues the 3 loads
        // BEFORE the exp burst so L1/L2 latency hides under it.
        const int ncn = nbase + ((ch + 1) & (NCH - 1)) * 32;
        bf16x8 qf_n  = *(const bf16x8*)(qrow + (size_t)(ncn + ln) * 8);
        bf16x8 va0_n = *(const bf16x8*)(vrow + ncn + hi * 8);
        bf16x8 va1_n = *(const bf16x8*)(vrow + ncn + 16 + hi * 8);

        v16f S = __builtin_amdgcn_mfma_f32_32x32x16_bf16(qf, kfragB, vzero,
                                                         0, 0, 0);

        float e0  = fast_exp2(S[0]),  e1  = fast_exp2(S[1]);
        float e2  = fast_exp2(S[2]),  e3  = fast_exp2(S[3]);
        float e4  = fast_exp2(S[4]),  e5  = fast_exp2(S[5]);
        float e6  = fast_exp2(S[6]),  e7  = fast_exp2(S[7]);
        float e8  = fast_exp2(S[8]),  e9  = fast_exp2(S[9]);
        float e10 = fast_exp2(S[10]), e11 = fast_exp2(S[11]);
        float e12 = fast_exp2(S[12]), e13 = fast_exp2(S[13]);
        float e14 = fast_exp2(S[14]), e15 = fast_exp2(S[15]);

        // Denominator partial for col m=ln (16 n-values this lane holds).
        den += (((e0 + e1) + (e2 + e3)) + ((e4 + e5) + (e6 + e7)))
             + (((e8 + e9) + (e10 + e11)) + ((e12 + e13) + (e14 + e15)));

        unsigned int pk0 = cvt_pk_bf16(e0,  e1);
        unsigned int pk1 = cvt_pk_bf16(e2,  e3);
        unsigned int pk2 = cvt_pk_bf16(e4,  e5);
        unsigned int pk3 = cvt_pk_bf16(e6,  e7);
        unsigned int pk4 = cvt_pk_bf16(e8,  e9);
        unsigned int pk5 = cvt_pk_bf16(e10, e11);
        unsigned int pk6 = cvt_pk_bf16(e12, e13);
        unsigned int pk7 = cvt_pk_bf16(e14, e15);

        // Lane-half exchange -> PV B-frags B[k=hi*8+j][col=ln] = E[n][m]
        u32x2 r02 = __builtin_amdgcn_permlane32_swap(pk0, pk2, false, false);
        u32x2 r13 = __builtin_amdgcn_permlane32_swap(pk1, pk3, false, false);
        u32x2 r46 = __builtin_amdgcn_permlane32_swap(pk4, pk6, false, false);
        u32x2 r57 = __builtin_amdgcn_permlane32_swap(pk5, pk7, false, false);

        union { unsigned int u[4]; bf16x8 f; } e0f, e1f;
        e0f.u[0] = r02[0]; e0f.u[1] = r13[0]; e0f.u[2] = r02[1]; e0f.u[3] = r13[1];
        e1f.u[0] = r46[0]; e1f.u[1] = r57[0]; e1f.u[2] = r46[1]; e1f.u[3] = r57[1];

        if (ch & 1) {
            acc1 = __builtin_amdgcn_mfma_f32_32x32x16_bf16(va0, e0f.f, acc1, 0, 0, 0);
            acc1 = __builtin_amdgcn_mfma_f32_32x32x16_bf16(va1, e1f.f, acc1, 0, 0, 0);
        } else {
            acc0 = __builtin_amdgcn_mfma_f32_32x32x16_bf16(va0, e0f.f, acc0, 0, 0, 0);
            acc0 = __builtin_amdgcn_mfma_f32_32x32x16_bf16(va1, e1f.f, acc0, 0, 0, 0);
        }

        qf = qf_n; va0 = va0_n; va1 = va1_n;
    }

    // Epilogue: C row io = r + 4*hi for r=0..3 -> rows 0..7 (= V outputs);
    // rows 8..31 garbage (skipped). Denominator row 8 from den.
    float* ap = attab + (size_t)b * 9 * NN + m0 + ln;
#pragma unroll
    for (int r = 0; r < 4; ++r)
        atomicAdd(ap + (size_t)(r + 4 * hi) * NN, acc0[r] + acc1[r]);
    float dtot = den + __shfl_xor(den, 32, 64);
    if (hi == 0)
        atomicAdd(ap + (size_t)8 * NN, dtot);
}

// R7-proven out. Grid (NN/1024, CC, BB); block 256; float4 per thread.
__global__ __launch_bounds__(256) void out_kernel(
        const float* __restrict__ x, const float* __restrict__ Wout,
        const float* __restrict__ attab, float* __restrict__ out) {
    const int t = threadIdx.x;
    const int c = blockIdx.y;
    const int b = blockIdx.z;
    const int m = (blockIdx.x * 256 + t) * 4;
    const float* ap = attab + (size_t)b * 9 * NN + m;
    v4f sum = *(const v4f*)(ap + (size_t)8 * NN);
    v4f s = {0.f, 0.f, 0.f, 0.f};
#pragma unroll
    for (int i = 0; i < CI; ++i) {
        float wgt = Wout[c * CI + i];               // uniform -> s_load
        v4f a = *(const v4f*)(ap + (size_t)i * NN);
        s.x = fmaf(wgt, a.x, s.x);
        s.y = fmaf(wgt, a.y, s.y);
        s.z = fmaf(wgt, a.z, s.z);
        s.w = fmaf(wgt, a.w, s.w);
    }
    size_t o = ((size_t)b * CC + c) * NN + m;
    v4f xv = *(const v4f*)(x + o);
    v4f r;
    r.x = xv.x + GAMMA * (s.x / sum.x);
    r.y = xv.y + GAMMA * (s.y / sum.y);
    r.z = xv.z + GAMMA * (s.z / sum.z);
    r.w = xv.w + GAMMA * (s.w / sum.w);
    *(v4f*)(out + o) = r;
}

extern "C" void kernel_launch(void* const* d_in, const int* in_sizes, int n_in,
                              void* d_out, int out_size, void* d_ws, size_t ws_size,
                              hipStream_t stream) {
    const float* x    = (const float*)d_in[0];
    const float* Wq   = (const float*)d_in[1];
    const float* Wk   = (const float*)d_in[2];
    const float* Wv   = (const float*)d_in[3];
    const float* Wout = (const float*)d_in[4];
    float* out = (float*)d_out;

    // ws: qbh [B][N][8] bf16 | kbh [B][N][8] bf16 | vbh [B][8][N] bf16 |
    //     attab [B][9][N] fp32
    __bf16* qbh = (__bf16*)d_ws;
    __bf16* kbh = qbh + (size_t)BB * NN * 8;
    __bf16* vbh = kbh + (size_t)BB * NN * 8;
    float* attab = (float*)(vbh + (size_t)BB * NN * 8);

    qkv_kernel<<<dim3(NN / 32, BB), 256, 0, stream>>>(x, Wq, Wk, Wv, qbh, kbh, vbh, attab);
    att_kernel<<<dim3(NN / 128, NSPLIT, BB), 256, 0, stream>>>(qbh, kbh, vbh, attab);
    out_kernel<<<dim3(NN / 1024, CC, BB), 256, 0, stream>>>(x, Wout, attab, out);
}